// Round 1
// baseline (1353.543 us; speedup 1.0000x reference)
//
#include <hip/hip_runtime.h>
#include <math.h>

#define T_DIM 8192
#define E_DIM 64
#define B_DIM 16
#define K_DIM 2048
#define N_PTS (B_DIM * T_DIM)      // 131072 points
#define N_ELEM (N_PTS * E_DIM)     // 8388608 elements

// ws layout:
//   [0..31]   : 4 doubles: commit_sum, fit_sum, x_sum, x_sumsq
//   [64..]    : float cn2[K_DIM]

__global__ void cn2_kernel(const float* __restrict__ cb, float* __restrict__ cn2) {
    int k = blockIdx.x * blockDim.x + threadIdx.x;
    if (k < K_DIM) {
        const float4* row = (const float4*)(cb + (size_t)k * E_DIM);
        float s = 0.f;
#pragma unroll
        for (int j = 0; j < E_DIM / 4; ++j) {
            float4 c = row[j];
            s = fmaf(c.x, c.x, s);
            s = fmaf(c.y, c.y, s);
            s = fmaf(c.z, c.z, s);
            s = fmaf(c.w, c.w, s);
        }
        cn2[k] = s;
    }
}

__global__ __launch_bounds__(256) void vq_main(
    const float* __restrict__ x, const float* __restrict__ cb,
    const float* __restrict__ cn2, float* __restrict__ out,
    double* __restrict__ accum)
{
    int n = blockIdx.x * 256 + threadIdx.x;        // point index, n = b*T + t
    int b = n >> 13;                               // / T_DIM
    int t = n & (T_DIM - 1);
    const float* xp = x + (size_t)b * E_DIM * T_DIM + t;

    // load the point into registers; accumulate sum and sumsq on the way
    float xv[E_DIM];
    float xn2 = 0.f, xsum = 0.f;
#pragma unroll
    for (int e = 0; e < E_DIM; ++e) {
        float v = xp[(size_t)e * T_DIM];
        xv[e] = v;
        xn2 = fmaf(v, v, xn2);
        xsum += v;
    }

    // ---- main K loop: track best-2 (value, index) of (cn2[k] - 2*dot) ----
    float d1 = 1e30f, d2 = 1e30f;
    int i1 = 0, i2 = 0;
    const float4* cb4 = (const float4*)cb;

    for (int k = 0; k < K_DIM; ++k) {
        float dotA = 0.f, dotB = 0.f;   // two chains for ILP
#pragma unroll
        for (int j = 0; j < E_DIM / 8; ++j) {
            float4 ca = cb4[(size_t)k * (E_DIM / 4) + j];
            float4 cbv = cb4[(size_t)k * (E_DIM / 4) + (E_DIM / 8) + j];
            dotA = fmaf(xv[4 * j + 0], ca.x, dotA);
            dotA = fmaf(xv[4 * j + 1], ca.y, dotA);
            dotA = fmaf(xv[4 * j + 2], ca.z, dotA);
            dotA = fmaf(xv[4 * j + 3], ca.w, dotA);
            dotB = fmaf(xv[E_DIM / 2 + 4 * j + 0], cbv.x, dotB);
            dotB = fmaf(xv[E_DIM / 2 + 4 * j + 1], cbv.y, dotB);
            dotB = fmaf(xv[E_DIM / 2 + 4 * j + 2], cbv.z, dotB);
            dotB = fmaf(xv[E_DIM / 2 + 4 * j + 3], cbv.w, dotB);
        }
        float dot = dotA + dotB;
        float d = fmaf(-2.f, dot, cn2[k]);

        bool lt1 = d < d1;
        bool lt2 = d < d2;
        float nd2 = d2; int ni2 = i2;
        if (lt2) { nd2 = d;  ni2 = k;  }
        if (lt1) { nd2 = d1; ni2 = i1; }   // lt1 implies old d1 demotes
        d2 = nd2; i2 = ni2;
        if (lt1) { d1 = d; i1 = k; }
    }

    // ---- exact refine of the two candidates with the direct form ----
    const float4* r1 = cb4 + (size_t)i1 * (E_DIM / 4);
    const float4* r2 = cb4 + (size_t)i2 * (E_DIM / 4);
    float e1 = 0.f, e2 = 0.f;
#pragma unroll
    for (int j = 0; j < E_DIM / 4; ++j) {
        float4 c1 = r1[j];
        float4 c2 = r2[j];
        float u;
        u = xv[4 * j + 0] - c1.x; e1 = fmaf(u, u, e1);
        u = xv[4 * j + 1] - c1.y; e1 = fmaf(u, u, e1);
        u = xv[4 * j + 2] - c1.z; e1 = fmaf(u, u, e1);
        u = xv[4 * j + 3] - c1.w; e1 = fmaf(u, u, e1);
        u = xv[4 * j + 0] - c2.x; e2 = fmaf(u, u, e2);
        u = xv[4 * j + 1] - c2.y; e2 = fmaf(u, u, e2);
        u = xv[4 * j + 2] - c2.z; e2 = fmaf(u, u, e2);
        u = xv[4 * j + 3] - c2.w; e2 = fmaf(u, u, e2);
    }
    bool pick2 = (e2 < e1) || (e2 == e1 && i2 < i1);  // first-index tie-break
    int idx = pick2 ? i2 : i1;
    float fitv = (pick2 ? d2 : d1) + xn2;             // expansion-form value

    // ---- gather chosen codeword, write transposed output, commit loss ----
    const float4* rw = cb4 + (size_t)idx * (E_DIM / 4);
    float* op = out + (size_t)b * E_DIM * T_DIM + t;
    float commit = 0.f;
#pragma unroll
    for (int j = 0; j < E_DIM / 4; ++j) {
        float4 c = rw[j];
        float df;
        op[(size_t)(4 * j + 0) * T_DIM] = c.x; df = c.x - xv[4 * j + 0]; commit = fmaf(df, df, commit);
        op[(size_t)(4 * j + 1) * T_DIM] = c.y; df = c.y - xv[4 * j + 1]; commit = fmaf(df, df, commit);
        op[(size_t)(4 * j + 2) * T_DIM] = c.z; df = c.z - xv[4 * j + 2]; commit = fmaf(df, df, commit);
        op[(size_t)(4 * j + 3) * T_DIM] = c.w; df = c.w - xv[4 * j + 3]; commit = fmaf(df, df, commit);
    }

    // ---- block reduction of the 4 scalars, one f64 atomic per block ----
    float v0 = commit, v1 = fitv, v2 = xsum, v3 = xn2;
#pragma unroll
    for (int off = 32; off > 0; off >>= 1) {
        v0 += __shfl_down(v0, off);
        v1 += __shfl_down(v1, off);
        v2 += __shfl_down(v2, off);
        v3 += __shfl_down(v3, off);
    }
    __shared__ float red[4][4];
    int wave = threadIdx.x >> 6;
    int lane = threadIdx.x & 63;
    if (lane == 0) {
        red[wave][0] = v0; red[wave][1] = v1; red[wave][2] = v2; red[wave][3] = v3;
    }
    __syncthreads();
    if (threadIdx.x == 0) {
        double s0 = 0, s1 = 0, s2 = 0, s3 = 0;
        for (int w = 0; w < 4; ++w) {
            s0 += (double)red[w][0];
            s1 += (double)red[w][1];
            s2 += (double)red[w][2];
            s3 += (double)red[w][3];
        }
        atomicAdd(&accum[0], s0);
        atomicAdd(&accum[1], s1);
        atomicAdd(&accum[2], s2);
        atomicAdd(&accum[3], s3);
    }
}

__global__ void finalize_kernel(const double* __restrict__ accum,
                                float* __restrict__ out_scalars)
{
    double commit = accum[0];
    double fit    = accum[1];
    double sum    = accum[2];
    double sumsq  = accum[3];
    out_scalars[0] = (float)(commit / (double)N_ELEM);
    out_scalars[1] = (float)(fit / (double)N_PTS);
    double mean = sum / (double)N_ELEM;
    double var  = sumsq / (double)N_ELEM - mean * mean;
    out_scalars[2] = (float)sqrt(var > 0.0 ? var : 0.0);
}

extern "C" void kernel_launch(void* const* d_in, const int* in_sizes, int n_in,
                              void* d_out, int out_size, void* d_ws, size_t ws_size,
                              hipStream_t stream) {
    const float* x  = (const float*)d_in[0];
    const float* cb = (const float*)d_in[1];
    float* out = (float*)d_out;
    double* accum = (double*)d_ws;
    float* cn2 = (float*)((char*)d_ws + 64);

    hipMemsetAsync(d_ws, 0, 64, stream);   // zero the 4 accumulators each call
    cn2_kernel<<<K_DIM / 256, 256, 0, stream>>>(cb, cn2);
    vq_main<<<N_PTS / 256, 256, 0, stream>>>(x, cb, cn2, out, accum);
    finalize_kernel<<<1, 1, 0, stream>>>(accum, out + N_ELEM);
}

// Round 2
// 681.746 us; speedup vs baseline: 1.9854x; 1.9854x over previous
//
#include <hip/hip_runtime.h>
#include <math.h>

#define T_DIM 8192
#define E_DIM 64
#define B_DIM 16
#define K_DIM 2048
#define N_PTS (B_DIM * T_DIM)      // 131072 points
#define N_ELEM (N_PTS * E_DIM)     // 8388608 elements

// ws layout:
//   [0..31]    : 4 doubles: commit_sum, fit_sum, x_sum, x_sumsq
//   [64..8255] : float cn2[K_DIM]
//   [8256..]   : float4 part[NCHUNK][N_PTS]  = {d1, bits(i1), d2, bits(i2)}

__global__ void cn2_kernel(const float* __restrict__ cb, float* __restrict__ cn2) {
    int k = blockIdx.x * blockDim.x + threadIdx.x;
    if (k < K_DIM) {
        const float4* row = (const float4*)(cb + (size_t)k * E_DIM);
        float s = 0.f;
#pragma unroll
        for (int j = 0; j < E_DIM / 4; ++j) {
            float4 c = row[j];
            s = fmaf(c.x, c.x, s);
            s = fmaf(c.y, c.y, s);
            s = fmaf(c.z, c.z, s);
            s = fmaf(c.w, c.w, s);
        }
        cn2[k] = s;
    }
}

// best-2 streaming update; strict < keeps the FIRST index on ties
#define UPD(dv, kk)                                   \
    {                                                 \
        bool lt1 = (dv) < d1;                         \
        bool lt2 = (dv) < d2;                         \
        float nd2 = lt1 ? d1 : (dv);                  \
        int ni2 = lt1 ? i1 : (kk);                    \
        if (lt2) { d2 = nd2; i2 = ni2; }              \
        if (lt1) { d1 = (dv); i1 = (kk); }            \
    }

__global__ __launch_bounds__(256) void vq_part(
    const float* __restrict__ x, const float* __restrict__ cb,
    const float* __restrict__ cn2, float4* __restrict__ part, int kspan)
{
    int n = blockIdx.x * 256 + threadIdx.x;        // point index
    int chunk = blockIdx.y;
    int b = n >> 13;
    int t = n & (T_DIM - 1);
    const float* xp = x + (size_t)b * E_DIM * T_DIM + t;

    float xv[E_DIM];
#pragma unroll
    for (int e = 0; e < E_DIM; ++e) xv[e] = xp[(size_t)e * T_DIM];

    int k0 = chunk * kspan;
    int k1 = k0 + kspan;
    float d1 = 1e30f, d2 = 1e30f;
    int i1 = 0, i2 = 0;
    const float4* cb4 = (const float4*)cb;

    for (int k = k0; k < k1; k += 2) {
        const float4* rowA = cb4 + (size_t)k * (E_DIM / 4);
        const float4* rowB = rowA + (E_DIM / 4);
        float aA0 = 0.f, aA1 = 0.f, aB0 = 0.f, aB1 = 0.f;   // 4 chains
#pragma unroll
        for (int j = 0; j < E_DIM / 8; ++j) {
            float4 cA0 = rowA[j];
            float4 cA1 = rowA[j + E_DIM / 8];
            float4 cB0 = rowB[j];
            float4 cB1 = rowB[j + E_DIM / 8];
            aA0 = fmaf(xv[4 * j + 0], cA0.x, aA0);
            aA0 = fmaf(xv[4 * j + 1], cA0.y, aA0);
            aA0 = fmaf(xv[4 * j + 2], cA0.z, aA0);
            aA0 = fmaf(xv[4 * j + 3], cA0.w, aA0);
            aA1 = fmaf(xv[E_DIM / 2 + 4 * j + 0], cA1.x, aA1);
            aA1 = fmaf(xv[E_DIM / 2 + 4 * j + 1], cA1.y, aA1);
            aA1 = fmaf(xv[E_DIM / 2 + 4 * j + 2], cA1.z, aA1);
            aA1 = fmaf(xv[E_DIM / 2 + 4 * j + 3], cA1.w, aA1);
            aB0 = fmaf(xv[4 * j + 0], cB0.x, aB0);
            aB0 = fmaf(xv[4 * j + 1], cB0.y, aB0);
            aB0 = fmaf(xv[4 * j + 2], cB0.z, aB0);
            aB0 = fmaf(xv[4 * j + 3], cB0.w, aB0);
            aB1 = fmaf(xv[E_DIM / 2 + 4 * j + 0], cB1.x, aB1);
            aB1 = fmaf(xv[E_DIM / 2 + 4 * j + 1], cB1.y, aB1);
            aB1 = fmaf(xv[E_DIM / 2 + 4 * j + 2], cB1.z, aB1);
            aB1 = fmaf(xv[E_DIM / 2 + 4 * j + 3], cB1.w, aB1);
        }
        float dA = fmaf(-2.f, aA0 + aA1, cn2[k]);
        float dB = fmaf(-2.f, aB0 + aB1, cn2[k + 1]);
        UPD(dA, k);
        UPD(dB, k + 1);
    }

    part[(size_t)chunk * N_PTS + n] =
        make_float4(d1, __int_as_float(i1), d2, __int_as_float(i2));
}

__global__ __launch_bounds__(256) void vq_finish(
    const float* __restrict__ x, const float* __restrict__ cb,
    const float4* __restrict__ part, int nchunk,
    float* __restrict__ out, double* __restrict__ accum)
{
    int n = blockIdx.x * 256 + threadIdx.x;
    int b = n >> 13;
    int t = n & (T_DIM - 1);
    const float* xp = x + (size_t)b * E_DIM * T_DIM + t;

    float xv[E_DIM];
    float xn2 = 0.f, xsum = 0.f;
#pragma unroll
    for (int e = 0; e < E_DIM; ++e) {
        float v = xp[(size_t)e * T_DIM];
        xv[e] = v;
        xn2 = fmaf(v, v, xn2);
        xsum += v;
    }

    // ---- merge per-chunk best-2 lists (lexicographic on (d, index)) ----
    float D1 = 1e30f, D2 = 1e30f;
    int I1 = 0x7fffffff, I2 = 0x7fffffff;
#define MERGE(dv, iv)                                                  \
    {                                                                  \
        bool b1 = ((dv) < D1) || ((dv) == D1 && (iv) < I1);            \
        bool b2 = ((dv) < D2) || ((dv) == D2 && (iv) < I2);            \
        if (b1) { D2 = D1; I2 = I1; D1 = (dv); I1 = (iv); }            \
        else if (b2) { D2 = (dv); I2 = (iv); }                         \
    }
    for (int c = 0; c < nchunk; ++c) {
        float4 p = part[(size_t)c * N_PTS + n];
        MERGE(p.x, __float_as_int(p.y));
        MERGE(p.z, __float_as_int(p.w));
    }

    // ---- exact refine of the two candidates with the direct form ----
    const float4* cb4 = (const float4*)cb;
    const float4* r1 = cb4 + (size_t)I1 * (E_DIM / 4);
    const float4* r2 = cb4 + (size_t)I2 * (E_DIM / 4);
    float e1 = 0.f, e2 = 0.f;
#pragma unroll
    for (int j = 0; j < E_DIM / 4; ++j) {
        float4 c1 = r1[j];
        float4 c2 = r2[j];
        float u;
        u = xv[4 * j + 0] - c1.x; e1 = fmaf(u, u, e1);
        u = xv[4 * j + 1] - c1.y; e1 = fmaf(u, u, e1);
        u = xv[4 * j + 2] - c1.z; e1 = fmaf(u, u, e1);
        u = xv[4 * j + 3] - c1.w; e1 = fmaf(u, u, e1);
        u = xv[4 * j + 0] - c2.x; e2 = fmaf(u, u, e2);
        u = xv[4 * j + 1] - c2.y; e2 = fmaf(u, u, e2);
        u = xv[4 * j + 2] - c2.z; e2 = fmaf(u, u, e2);
        u = xv[4 * j + 3] - c2.w; e2 = fmaf(u, u, e2);
    }
    bool pick2 = (e2 < e1) || (e2 == e1 && I2 < I1);
    int idx = pick2 ? I2 : I1;
    float fitv = (pick2 ? D2 : D1) + xn2;

    // ---- gather chosen codeword, write transposed output, commit loss ----
    const float4* rw = cb4 + (size_t)idx * (E_DIM / 4);
    float* op = out + (size_t)b * E_DIM * T_DIM + t;
    float commit = 0.f;
#pragma unroll
    for (int j = 0; j < E_DIM / 4; ++j) {
        float4 c = rw[j];
        float df;
        op[(size_t)(4 * j + 0) * T_DIM] = c.x; df = c.x - xv[4 * j + 0]; commit = fmaf(df, df, commit);
        op[(size_t)(4 * j + 1) * T_DIM] = c.y; df = c.y - xv[4 * j + 1]; commit = fmaf(df, df, commit);
        op[(size_t)(4 * j + 2) * T_DIM] = c.z; df = c.z - xv[4 * j + 2]; commit = fmaf(df, df, commit);
        op[(size_t)(4 * j + 3) * T_DIM] = c.w; df = c.w - xv[4 * j + 3]; commit = fmaf(df, df, commit);
    }

    // ---- block reduction of the 4 scalars, one f64 atomic per block ----
    float v0 = commit, v1 = fitv, v2 = xsum, v3 = xn2;
#pragma unroll
    for (int off = 32; off > 0; off >>= 1) {
        v0 += __shfl_down(v0, off);
        v1 += __shfl_down(v1, off);
        v2 += __shfl_down(v2, off);
        v3 += __shfl_down(v3, off);
    }
    __shared__ float red[4][4];
    int wave = threadIdx.x >> 6;
    int lane = threadIdx.x & 63;
    if (lane == 0) {
        red[wave][0] = v0; red[wave][1] = v1; red[wave][2] = v2; red[wave][3] = v3;
    }
    __syncthreads();
    if (threadIdx.x == 0) {
        double s0 = 0, s1 = 0, s2 = 0, s3 = 0;
        for (int w = 0; w < 4; ++w) {
            s0 += (double)red[w][0];
            s1 += (double)red[w][1];
            s2 += (double)red[w][2];
            s3 += (double)red[w][3];
        }
        atomicAdd(&accum[0], s0);
        atomicAdd(&accum[1], s1);
        atomicAdd(&accum[2], s2);
        atomicAdd(&accum[3], s3);
    }
}

__global__ void finalize_kernel(const double* __restrict__ accum,
                                float* __restrict__ out_scalars)
{
    double commit = accum[0];
    double fit    = accum[1];
    double sum    = accum[2];
    double sumsq  = accum[3];
    out_scalars[0] = (float)(commit / (double)N_ELEM);
    out_scalars[1] = (float)(fit / (double)N_PTS);
    double mean = sum / (double)N_ELEM;
    double var  = sumsq / (double)N_ELEM - mean * mean;
    out_scalars[2] = (float)sqrt(var > 0.0 ? var : 0.0);
}

extern "C" void kernel_launch(void* const* d_in, const int* in_sizes, int n_in,
                              void* d_out, int out_size, void* d_ws, size_t ws_size,
                              hipStream_t stream) {
    const float* x  = (const float*)d_in[0];
    const float* cb = (const float*)d_in[1];
    float* out = (float*)d_out;
    double* accum = (double*)d_ws;
    float* cn2 = (float*)((char*)d_ws + 64);
    float4* part = (float4*)((char*)d_ws + 8256);

    // pick chunk count by available scratch (deterministic in ws_size)
    int NC = 1;
    if (ws_size >= 8256 + (size_t)N_PTS * 4 * sizeof(float4)) NC = 4;
    else if (ws_size >= 8256 + (size_t)N_PTS * 2 * sizeof(float4)) NC = 2;

    hipMemsetAsync(d_ws, 0, 64, stream);   // zero the 4 accumulators each call
    cn2_kernel<<<K_DIM / 256, 256, 0, stream>>>(cb, cn2);
    dim3 gridA(N_PTS / 256, NC);
    vq_part<<<gridA, 256, 0, stream>>>(x, cb, cn2, part, K_DIM / NC);
    vq_finish<<<N_PTS / 256, 256, 0, stream>>>(x, cb, part, NC, out, accum);
    finalize_kernel<<<1, 1, 0, stream>>>(accum, out + N_ELEM);
}

// Round 3
// 173.679 us; speedup vs baseline: 7.7933x; 3.9253x over previous
//
#include <hip/hip_runtime.h>
#include <math.h>

#define T_DIM 8192
#define E_DIM 64
#define B_DIM 16
#define K_DIM 2048
#define N_PTS (B_DIM * T_DIM)      // 131072 points
#define N_ELEM (N_PTS * E_DIM)     // 8388608 elements

typedef __attribute__((ext_vector_type(8))) short short8;
typedef __attribute__((ext_vector_type(4))) float f32x4;

// ws layout:
//   [0..63]      : 4 doubles: commit_sum, fit_sum, x_sum, x_sumsq
//   [64..8255]   : float cn2b[K_DIM]  (= ||c||^2 + 256 bias for positive-packed compare)
//   [8256..+2MB) : uint2 part[2][N_PTS]  (cw candidates from wc=0 and wc=1 wave columns)
//   [then +512KB): swizzled bf16 codebook (hi+lo), frag-coalesced layout
#define WS_CN2  64
#define WS_PART 8256
#define WS_SWZ  (8256 + (size_t)2 * N_PTS * 8)

__global__ void prep_cn2(const float* __restrict__ cb, float* __restrict__ cn2b) {
    int k = blockIdx.x * blockDim.x + threadIdx.x;
    if (k < K_DIM) {
        const float4* row = (const float4*)(cb + (size_t)k * E_DIM);
        float s = 0.f;
#pragma unroll
        for (int j = 0; j < E_DIM / 4; ++j) {
            float4 c = row[j];
            s = fmaf(c.x, c.x, s);
            s = fmaf(c.y, c.y, s);
            s = fmaf(c.z, c.z, s);
            s = fmaf(c.w, c.w, s);
        }
        cn2b[k] = s + 256.f;
    }
}

__device__ __forceinline__ unsigned short f2bf_rne(float v) {
    unsigned int u = __float_as_uint(v);
    return (unsigned short)((u + 0x7FFFu + ((u >> 16) & 1u)) >> 16);
}

// Swizzled codebook: for cw-tile c16 (16 codewords), the B-frag for
// (hl, estep) is 64 lanes x 16B contiguous: lane l <-> cw=c16*16+(l&15),
// e = es*32 + (l>>4)*8 .. +8.  ushort offset = c16*2048 + hl*1024 + es*512 + l*8
__global__ void prep_swz(const float* __restrict__ cb, unsigned short* __restrict__ swz) {
    int tid = blockIdx.x * 256 + threadIdx.x;   // 32768 threads
    int l   = tid & 63;
    int es  = (tid >> 6) & 1;
    int hl  = (tid >> 7) & 1;
    int c16 = tid >> 8;
    int cw  = c16 * 16 + (l & 15);
    int e0  = es * 32 + ((l >> 4) * 8);
    const float* src = cb + (size_t)cw * E_DIM + e0;
    short8 v;
#pragma unroll
    for (int j = 0; j < 8; ++j) {
        float f = src[j];
        unsigned short h = f2bf_rne(f);
        if (hl == 0) {
            v[j] = (short)h;
        } else {
            float hf = __uint_as_float(((unsigned int)h) << 16);
            v[j] = (short)f2bf_rne(f - hf);
        }
    }
    *(short8*)(swz + (size_t)c16 * 2048 + hl * 1024 + es * 512 + l * 8) = v;
}

__global__ __launch_bounds__(256) void vq_mfma(
    const float* __restrict__ x, const unsigned short* __restrict__ swz,
    const float* __restrict__ cn2b, uint2* __restrict__ part)
{
    const int l  = threadIdx.x & 63;
    const int w  = threadIdx.x >> 6;
    const int wr = w >> 1;           // row-wave: 0,1 (64 points each)
    const int wc = w & 1;            // col-wave: 0,1 (half of codebook each)
    const int lm = l & 15;
    const int lg = l >> 4;
    const int n0 = blockIdx.x * 128 + wr * 64;

    // ---- A fragments: convert x (fp32, [B][E][T]) to bf16 hi/lo, resident ----
    short8 Ah[4][2], Al[4][2];
#pragma unroll
    for (int rf = 0; rf < 4; ++rf) {
        int n  = n0 + rf * 16 + lm;
        int bb = n >> 13;
        int tt = n & (T_DIM - 1);
#pragma unroll
        for (int es = 0; es < 2; ++es) {
            int e0 = es * 32 + lg * 8;
            const float* xp = x + ((size_t)bb * E_DIM + e0) * T_DIM + tt;
#pragma unroll
            for (int j = 0; j < 8; ++j) {
                float v = xp[(size_t)j * T_DIM];
                unsigned short h = f2bf_rne(v);
                float hf = __uint_as_float(((unsigned int)h) << 16);
                Ah[rf][es][j] = (short)h;
                Al[rf][es][j] = (short)f2bf_rne(v - hf);
            }
        }
    }

    // per-lane best-2 packed state per row-slot (16 = 4 rowfrags x 4 acc rows)
    unsigned int b1[16], b2[16];
#pragma unroll
    for (int i = 0; i < 16; ++i) { b1[i] = 0xFFFFFFFFu; b2[i] = 0xFFFFFFFFu; }

    const short8* swz8 = (const short8*)swz;
    const f32x4 zero = {0.f, 0.f, 0.f, 0.f};

    for (int s = 0; s < 32; ++s) {
        short8 Bh[2][2], Bl[2][2];
        float c2[2];
#pragma unroll
        for (int cf = 0; cf < 2; ++cf) {
            int c16 = s * 4 + wc * 2 + cf;
            size_t base = (size_t)c16 * 256;            // short8 units (4096 B / 16)
#pragma unroll
            for (int es = 0; es < 2; ++es) {
                Bh[cf][es] = swz8[base + es * 64 + l];          // hi
                Bl[cf][es] = swz8[base + 128 + es * 64 + l];    // lo
            }
            c2[cf] = cn2b[s * 64 + wc * 32 + cf * 16 + lm];
        }
#pragma unroll
        for (int rf = 0; rf < 4; ++rf) {
#pragma unroll
            for (int cf = 0; cf < 2; ++cf) {
                f32x4 acc;
                acc = __builtin_amdgcn_mfma_f32_16x16x32_bf16(Ah[rf][0], Bh[cf][0], zero, 0, 0, 0);
                acc = __builtin_amdgcn_mfma_f32_16x16x32_bf16(Ah[rf][1], Bh[cf][1], acc,  0, 0, 0);
                acc = __builtin_amdgcn_mfma_f32_16x16x32_bf16(Ah[rf][0], Bl[cf][0], acc,  0, 0, 0);
                acc = __builtin_amdgcn_mfma_f32_16x16x32_bf16(Ah[rf][1], Bl[cf][1], acc,  0, 0, 0);
                acc = __builtin_amdgcn_mfma_f32_16x16x32_bf16(Al[rf][0], Bh[cf][0], acc,  0, 0, 0);
                acc = __builtin_amdgcn_mfma_f32_16x16x32_bf16(Al[rf][1], Bh[cf][1], acc,  0, 0, 0);
                unsigned int orv = ((unsigned int)s << 1) | (unsigned int)cf;
#pragma unroll
                for (int r = 0; r < 4; ++r) {
                    float d = fmaf(-2.f, acc[r], c2[cf]);   // >0 by +256 bias
                    unsigned int p = (__float_as_uint(d) & 0xFFFFFFC0u) | orv;
                    int slot = rf * 4 + r;
                    unsigned int t1 = b1[slot];
                    b2[slot] = min(b2[slot], max(t1, p));
                    b1[slot] = min(t1, p);
                }
            }
        }
    }

    // ---- cross-lane merge within 16-lane groups; write candidate indices ----
#pragma unroll
    for (int slot = 0; slot < 16; ++slot) {
        unsigned int p1 = b1[slot], p2 = b2[slot];
        unsigned int d1 = p1 & 0xFFFFFFC0u;
        unsigned int d2 = p2 & 0xFFFFFFC0u;
        unsigned int scf1 = p1 & 63u, scf2 = p2 & 63u;
        unsigned int cw1 = ((scf1 >> 1) << 6) | ((unsigned)wc << 5) | ((scf1 & 1u) << 4) | (unsigned)lm;
        unsigned int cw2 = ((scf2 >> 1) << 6) | ((unsigned)wc << 5) | ((scf2 & 1u) << 4) | (unsigned)lm;
#pragma unroll
        for (int off = 1; off < 16; off <<= 1) {
            unsigned int od1 = (unsigned int)__shfl_xor((int)d1, off, 16);
            unsigned int oc1 = (unsigned int)__shfl_xor((int)cw1, off, 16);
            unsigned int od2 = (unsigned int)__shfl_xor((int)d2, off, 16);
            unsigned int oc2 = (unsigned int)__shfl_xor((int)cw2, off, 16);
            // merge two sorted best-2 lists, lexicographic on (d, cw)
            bool o1lt = (od1 < d1) || (od1 == d1 && oc1 < cw1);
            unsigned int m1d = o1lt ? od1 : d1,  m1c = o1lt ? oc1 : cw1;
            unsigned int x1d = o1lt ? d1  : od1, x1c = o1lt ? cw1 : oc1;  // max of firsts
            bool o2lt = (od2 < d2) || (od2 == d2 && oc2 < cw2);
            unsigned int m2d = o2lt ? od2 : d2,  m2c = o2lt ? oc2 : cw2;  // min of seconds
            bool xlt = (x1d < m2d) || (x1d == m2d && x1c < m2c);
            d1 = m1d; cw1 = m1c;
            d2 = xlt ? x1d : m2d;
            cw2 = xlt ? x1c : m2c;
        }
        if (lm == slot) {
            int rf = slot >> 2, r = slot & 3;
            int n = n0 + rf * 16 + lg * 4 + r;
            part[(size_t)wc * N_PTS + n] = make_uint2(cw1, cw2);
        }
    }
}

__global__ __launch_bounds__(256) void vq_finish(
    const float* __restrict__ x, const float* __restrict__ cb,
    const uint2* __restrict__ part,
    float* __restrict__ out, double* __restrict__ accum)
{
    int n = blockIdx.x * 256 + threadIdx.x;
    int b = n >> 13;
    int t = n & (T_DIM - 1);
    const float* xp = x + (size_t)b * E_DIM * T_DIM + t;

    float xv[E_DIM];
    float xn2 = 0.f, xsum = 0.f;
#pragma unroll
    for (int e = 0; e < E_DIM; ++e) {
        float v = xp[(size_t)e * T_DIM];
        xv[e] = v;
        xn2 = fmaf(v, v, xn2);
        xsum += v;
    }

    uint2 pa = part[n];
    uint2 pb = part[(size_t)N_PTS + n];
    int I0 = (int)pa.x, I1 = (int)pa.y, I2 = (int)pb.x, I3 = (int)pb.y;

    // ---- exact refine of 4 candidates (direct squared distance) ----
    const float4* cb4 = (const float4*)cb;
    const float4* r0 = cb4 + (size_t)I0 * (E_DIM / 4);
    const float4* r1 = cb4 + (size_t)I1 * (E_DIM / 4);
    const float4* r2 = cb4 + (size_t)I2 * (E_DIM / 4);
    const float4* r3 = cb4 + (size_t)I3 * (E_DIM / 4);
    float e0 = 0.f, e1 = 0.f, e2 = 0.f, e3 = 0.f;
#pragma unroll
    for (int j = 0; j < E_DIM / 4; ++j) {
        float4 c0 = r0[j], c1 = r1[j], c2 = r2[j], c3 = r3[j];
        float u;
        u = xv[4*j+0] - c0.x; e0 = fmaf(u, u, e0);
        u = xv[4*j+1] - c0.y; e0 = fmaf(u, u, e0);
        u = xv[4*j+2] - c0.z; e0 = fmaf(u, u, e0);
        u = xv[4*j+3] - c0.w; e0 = fmaf(u, u, e0);
        u = xv[4*j+0] - c1.x; e1 = fmaf(u, u, e1);
        u = xv[4*j+1] - c1.y; e1 = fmaf(u, u, e1);
        u = xv[4*j+2] - c1.z; e1 = fmaf(u, u, e1);
        u = xv[4*j+3] - c1.w; e1 = fmaf(u, u, e1);
        u = xv[4*j+0] - c2.x; e2 = fmaf(u, u, e2);
        u = xv[4*j+1] - c2.y; e2 = fmaf(u, u, e2);
        u = xv[4*j+2] - c2.z; e2 = fmaf(u, u, e2);
        u = xv[4*j+3] - c2.w; e2 = fmaf(u, u, e2);
        u = xv[4*j+0] - c3.x; e3 = fmaf(u, u, e3);
        u = xv[4*j+1] - c3.y; e3 = fmaf(u, u, e3);
        u = xv[4*j+2] - c3.z; e3 = fmaf(u, u, e3);
        u = xv[4*j+3] - c3.w; e3 = fmaf(u, u, e3);
    }
    float eb = e0; int ib = I0;
    if ((e1 < eb) || (e1 == eb && I1 < ib)) { eb = e1; ib = I1; }
    if ((e2 < eb) || (e2 == eb && I2 < ib)) { eb = e2; ib = I2; }
    if ((e3 < eb) || (e3 == eb && I3 < ib)) { eb = e3; ib = I3; }
    float fitv = eb;
    int idx = ib;

    // ---- gather chosen codeword, write transposed output, commit loss ----
    const float4* rw = cb4 + (size_t)idx * (E_DIM / 4);
    float* op = out + (size_t)b * E_DIM * T_DIM + t;
    float commit = 0.f;
#pragma unroll
    for (int j = 0; j < E_DIM / 4; ++j) {
        float4 c = rw[j];
        float df;
        op[(size_t)(4*j+0) * T_DIM] = c.x; df = c.x - xv[4*j+0]; commit = fmaf(df, df, commit);
        op[(size_t)(4*j+1) * T_DIM] = c.y; df = c.y - xv[4*j+1]; commit = fmaf(df, df, commit);
        op[(size_t)(4*j+2) * T_DIM] = c.z; df = c.z - xv[4*j+2]; commit = fmaf(df, df, commit);
        op[(size_t)(4*j+3) * T_DIM] = c.w; df = c.w - xv[4*j+3]; commit = fmaf(df, df, commit);
    }

    // ---- block reduction of the 4 scalars, one f64 atomic per block ----
    float v0 = commit, v1 = fitv, v2 = xsum, v3 = xn2;
#pragma unroll
    for (int off = 32; off > 0; off >>= 1) {
        v0 += __shfl_down(v0, off);
        v1 += __shfl_down(v1, off);
        v2 += __shfl_down(v2, off);
        v3 += __shfl_down(v3, off);
    }
    __shared__ float red[4][4];
    int wave = threadIdx.x >> 6;
    int lane = threadIdx.x & 63;
    if (lane == 0) {
        red[wave][0] = v0; red[wave][1] = v1; red[wave][2] = v2; red[wave][3] = v3;
    }
    __syncthreads();
    if (threadIdx.x == 0) {
        double s0 = 0, s1 = 0, s2 = 0, s3 = 0;
        for (int wv = 0; wv < 4; ++wv) {
            s0 += (double)red[wv][0];
            s1 += (double)red[wv][1];
            s2 += (double)red[wv][2];
            s3 += (double)red[wv][3];
        }
        atomicAdd(&accum[0], s0);
        atomicAdd(&accum[1], s1);
        atomicAdd(&accum[2], s2);
        atomicAdd(&accum[3], s3);
    }
}

__global__ void finalize_kernel(const double* __restrict__ accum,
                                float* __restrict__ out_scalars)
{
    double commit = accum[0];
    double fit    = accum[1];
    double sum    = accum[2];
    double sumsq  = accum[3];
    out_scalars[0] = (float)(commit / (double)N_ELEM);
    out_scalars[1] = (float)(fit / (double)N_PTS);
    double mean = sum / (double)N_ELEM;
    double var  = sumsq / (double)N_ELEM - mean * mean;
    out_scalars[2] = (float)sqrt(var > 0.0 ? var : 0.0);
}

extern "C" void kernel_launch(void* const* d_in, const int* in_sizes, int n_in,
                              void* d_out, int out_size, void* d_ws, size_t ws_size,
                              hipStream_t stream) {
    const float* x  = (const float*)d_in[0];
    const float* cb = (const float*)d_in[1];
    float* out = (float*)d_out;
    double* accum = (double*)d_ws;
    float* cn2b = (float*)((char*)d_ws + WS_CN2);
    uint2* part = (uint2*)((char*)d_ws + WS_PART);
    unsigned short* swz = (unsigned short*)((char*)d_ws + WS_SWZ);

    hipMemsetAsync(d_ws, 0, 64, stream);   // zero the 4 scalar accumulators
    prep_cn2<<<K_DIM / 256, 256, 0, stream>>>(cb, cn2b);
    prep_swz<<<128, 256, 0, stream>>>(cb, swz);
    vq_mfma<<<N_PTS / 128, 256, 0, stream>>>(x, swz, cn2b, part);
    vq_finish<<<N_PTS / 256, 256, 0, stream>>>(x, cb, part, out, accum);
    finalize_kernel<<<1, 1, 0, stream>>>(accum, out + N_ELEM);
}